// Round 7
// baseline (429.276 us; speedup 1.0000x reference)
//
#include <hip/hip_runtime.h>

// MyConv2D: N=32, Cin=128, H=W=56, Cout=256, K=3, stride=1, pad=1, fp32.
// R7: occupancy fix. Single-buffered 64KB LDS (was 128KB dbuf) -> 2 blocks/CU
// resident; all 392 blocks co-resident (no 2-round tail); cross-block wave
// diversity hides staging drain + barrier convergence (the m97 "implicit
// wave-level overlap" that 1 block/CU structurally lacked — why R4-R6
// schedule edits were all null). launch_bounds(512,4) caps VGPR at 128.
// Tile body: 24 ds_read_b128 + 64 MFMA, compiler-scheduled (no asm fences);
// 3 barriers/K-tile.

typedef unsigned short u16;
typedef _Float16 f16x8 __attribute__((ext_vector_type(8)));
typedef float f32x4 __attribute__((ext_vector_type(4)));

#define CIN    128
#define COUT   256
#define HW     56
#define NPIX   3136        // 56*56
#define TOTPIX 100352      // 32*3136
#define NKT    18          // K-tiles of 64 ic: 9 taps * 2 ic-halves

#define WAITVM0 asm volatile("s_waitcnt vmcnt(0)" ::: "memory")
#define BARRIER asm volatile("s_barrier" ::: "memory")

__device__ __forceinline__ void gload16(const void* g, void* l) {
  __builtin_amdgcn_global_load_lds(
      (const __attribute__((address_space(1))) void*)g,
      (__attribute__((address_space(3))) void*)l, 16, 0, 0);
}

__device__ __forceinline__ u16 f2h(float f) {
  _Float16 h = (_Float16)f;
  return __builtin_bit_cast(u16, h);
}

// ---- prep_w: W[oc][ic][3][3] fp32 -> Wt fp16 (unchanged).
// e: j=e&7, ocl=(e>>3)&127, k8=(e>>10)&7, half=(e>>13)&1, t=e>>14.
__global__ void prep_w(const float* __restrict__ W, u16* __restrict__ Wt,
                       u16* __restrict__ zp) {
  int e = blockIdx.x * 256 + threadIdx.x;     // 1152 * 256 = 294912
  if (blockIdx.x == 0 && threadIdx.x < 128) zp[threadIdx.x] = 0;
  int j    = e & 7;
  int ocl  = (e >> 3) & 127;
  int k8   = (e >> 10) & 7;
  int half = (e >> 13) & 1;
  int t    = e >> 14;                         // 0..17
  int oc = half * 128 + ocl;
  int ic = (t & 1) * 64 + k8 * 8 + j;
  Wt[e] = f2h(W[(oc * CIN + ic) * 9 + (t >> 1)]);
}

// ---- prep_x: x NCHW fp32 -> xt [n][g=ic/8][pix][8ic] fp16 (unchanged).
__global__ void prep_x(const float* __restrict__ x, u16* __restrict__ xt) {
  __shared__ unsigned int tile[64 * 65];      // [pix][icpair], +1 pad
  int b = blockIdx.x;                         // 1568 = 32 * 49
  int n = b / 49;
  int hw0 = (b % 49) * 64;
  int tid = threadIdx.x;
  const float* xb = x + (size_t)n * CIN * NPIX + hw0;
  #pragma unroll
  for (int i = 0; i < 16; ++i) {
    int e = tid + i * 256;
    int icp = e >> 6;
    int pix = e & 63;
    float a = xb[(size_t)(2 * icp) * NPIX + pix];
    float c = xb[(size_t)(2 * icp + 1) * NPIX + pix];
    tile[pix * 65 + icp] = (unsigned)f2h(a) | ((unsigned)f2h(c) << 16);
  }
  __syncthreads();
  #pragma unroll
  for (int i = 0; i < 4; ++i) {
    int e = tid + i * 256;
    int g = e >> 6;
    int pix = e & 63;
    uint4 v;
    v.x = tile[pix * 65 + g * 4 + 0];
    v.y = tile[pix * 65 + g * 4 + 1];
    v.z = tile[pix * 65 + g * 4 + 2];
    v.w = tile[pix * 65 + g * 4 + 3];
    *(uint4*)(xt + ((size_t)(n * 16 + g) * NPIX + hw0 + pix) * 8) = v;
  }
}

// MFMA quadrant: 4 m-frags x 2 n-frags x 2 k-steps = 16 MFMA.
#define QUAD(MH, NH)                                                          \
  do {                                                                        \
    __builtin_amdgcn_s_setprio(1);                                            \
    _Pragma("unroll") for (int mq = 0; mq < 4; ++mq)                          \
    _Pragma("unroll") for (int nf = 0; nf < 2; ++nf)                          \
    _Pragma("unroll") for (int kk = 0; kk < 2; ++kk)                          \
      acc[(MH)*4 + mq][(NH)*2 + nf] =                                         \
          __builtin_amdgcn_mfma_f32_16x16x32_f16(                             \
              af[mq][kk], bf[(NH)][nf][kk], acc[(MH)*4 + mq][(NH)*2 + nf],    \
              0, 0, 0);                                                       \
    __builtin_amdgcn_s_setprio(0);                                            \
  } while (0)

#define READB(NH)                                                             \
  do {                                                                        \
    _Pragma("unroll") for (int nf = 0; nf < 2; ++nf)                          \
    _Pragma("unroll") for (int kk = 0; kk < 2; ++kk)                          \
      bf[(NH)][nf][kk] = *(const f16x8*)&lds[16384 + bhalf * 8192 +           \
          ((kk * 4 + lg) * 128 + bpl + (NH)*32 + nf * 16) * 8];               \
  } while (0)

__global__ __launch_bounds__(512, 4) void conv_mfma(
    const u16* __restrict__ Wt, const u16* __restrict__ xt,
    const float* __restrict__ bias, float* __restrict__ out,
    const u16* __restrict__ zp) {
  // LDS (single buffer, 64KB): A: [half][k8][ocl][8] 32KB | B: same-shape 32KB
  __shared__ __align__(16) u16 lds[32768];

  int tid  = threadIdx.x;                     // 0..511
  int lane = tid & 63;
  int wv   = tid >> 6;                        // 0..7
  int bid  = blockIdx.x;                      // 0..391
  int ptile = (bid & 7) * 49 + (bid >> 3);    // XCD swizzle (392 = 8*49)

  int wm = wv >> 2, wn = wv & 3;              // 2M x 4N waves
  int l15 = lane & 15, lg = lane >> 4;
  int bhalf = wn >> 1;
  int bpl = (wn & 1) * 64 + l15;

  // B staging: thread t owns granules (k8=tph, pixl) and (k8=tph+4, pixl).
  int pixl = tid & 127, tph = tid >> 7;       // tph 0..3
  int p0 = ptile * 256 + pixl, p1 = p0 + 128;
  int n0 = p0 / NPIX, r0 = p0 % NPIX, y0 = r0 / HW, x0 = r0 % HW;
  int n1 = p1 / NPIX, r1 = p1 % NPIX, y1 = r1 / HW, x1 = r1 % HW;
  const char* xtb = (const char*)xt;
  const char* wsrc = (const char*)Wt + tid * 16;
  const char* zpc = (const char*)zp;

  auto stageA = [&](int tn, int h) {
    const char* src = wsrc + (size_t)(tn * 2048 + h * 1024) * 16;
    u16* dst = &lds[h * 8192 + tid * 8];
    gload16(src, dst);
    gload16(src + 8192, dst + 4096);
  };
  // B source for (tap, ich, pix-half h): granule (g = ich*8 + tph, rsh).
  auto bsrc = [&](int tap, int ich, int h) -> const char* {
    int t3 = tap / 3;
    int dh = t3 - 1, dw = (tap - t3 * 3) - 1;
    int y = (h ? y1 : y0) + dh, xx = (h ? x1 : x0) + dw;
    if ((unsigned)y >= HW || (unsigned)xx >= HW) return zpc;
    int n = h ? n1 : n0;
    int rsh = (h ? r1 : r0) + dh * HW + dw;
    return xtb + ((size_t)(n * 16 + ich * 8 + tph) * NPIX + rsh) * 16;
  };
  auto stageB = [&](int h, const char* src) {
    u16* dst = &lds[16384 + h * 8192 + tid * 8];
    gload16(src, dst);
    gload16(src == zpc ? zpc : src + (size_t)4 * NPIX * 16, dst + 4096);
  };

  f32x4 acc[8][4] = {};
  f16x8 af[4][2], bf[2][2][2];

  auto readA = [&](int mh) {
    #pragma unroll
    for (int mq = 0; mq < 4; ++mq)
      #pragma unroll
      for (int kk = 0; kk < 2; ++kk)
        af[mq][kk] = *(const f16x8*)&lds[wm * 8192 +
            ((kk * 4 + lg) * 128 + mh * 64 + mq * 16 + l15) * 8];
  };

  // Prologue: stage K-tile 0 (8 loads/thread), rendezvous.
  stageA(0, 0); stageB(0, bsrc(0, 0, 0));
  stageA(0, 1); stageB(1, bsrc(0, 0, 1));
  WAITVM0; BARRIER;

  for (int t = 0; t < NKT; ++t) {
    // Compute tile t from the single buffer; compiler schedules reads/MFMA
    // with fine-grained lgkmcnt. Quad order keeps af-liveness to one half.
    readA(0); READB(0);
    QUAD(0, 0);
    READB(1);
    QUAD(0, 1);
    readA(1);
    QUAD(1, 1);
    QUAD(1, 0);
    BARRIER;                                  // all waves done reading tile t
    if (t + 1 < NKT) {
      int tn = t + 1;
      stageA(tn, 0); stageB(0, bsrc(tn >> 1, tn & 1, 0));
      stageA(tn, 1); stageB(1, bsrc(tn >> 1, tn & 1, 1));
      WAITVM0; BARRIER;                       // tile t+1 fully in LDS
    }
  }

  // Epilogue. C/D: row(oc) = lg*4 + reg, col(pix) = l15.
  float* ob[4];
  #pragma unroll
  for (int nf4 = 0; nf4 < 4; ++nf4) {
    int p = ptile * 256 + wn * 64 + nf4 * 16 + l15;
    int n = p / NPIX, hw = p % NPIX;
    ob[nf4] = out + (size_t)n * COUT * NPIX + hw;
  }
  #pragma unroll
  for (int mi = 0; mi < 8; ++mi) {
    int oc = wm * 128 + mi * 16 + lg * 4;
    f32x4 bv = *(const f32x4*)&bias[oc];
    #pragma unroll
    for (int r = 0; r < 4; ++r) {
      size_t row = (size_t)(oc + r) * NPIX;
      #pragma unroll
      for (int nf4 = 0; nf4 < 4; ++nf4)
        ob[nf4][row] = acc[mi][nf4][r] + bv[r];
    }
  }
}

// ---- fallback (only if ws too small): naive fp32 direct conv
__global__ void conv_naive(const float* __restrict__ x, const float* __restrict__ W,
                           const float* __restrict__ b, float* __restrict__ out) {
  int idx = blockIdx.x * 256 + threadIdx.x;
  int hw = idx % NPIX;
  int tmp = idx / NPIX;
  int oc = tmp % COUT;
  int n = tmp / COUT;
  int h = hw / HW, w = hw % HW;
  float acc = b[oc];
  for (int ic = 0; ic < CIN; ++ic) {
    const float* xr = x + (size_t)(n * CIN + ic) * NPIX;
    const float* wr = W + (size_t)(oc * CIN + ic) * 9;
    #pragma unroll
    for (int kh = 0; kh < 3; ++kh) {
      int ih = h + kh - 1;
      if ((unsigned)ih >= HW) continue;
      #pragma unroll
      for (int kw = 0; kw < 3; ++kw) {
        int iw = w + kw - 1;
        if ((unsigned)iw >= HW) continue;
        acc += xr[ih * HW + iw] * wr[kh * 3 + kw];
      }
    }
  }
  out[idx] = acc;
}

extern "C" void kernel_launch(void* const* d_in, const int* in_sizes, int n_in,
                              void* d_out, int out_size, void* d_ws, size_t ws_size,
                              hipStream_t stream) {
  const float* x = (const float*)d_in[0];
  const float* W = (const float*)d_in[1];
  const float* b = (const float*)d_in[2];
  float* out = (float*)d_out;

  const size_t ZP_OFF = 0;                    // 256 B zero page
  const size_t WT_OFF = 256;                  // 294912 * 2 = 589824 B
  const size_t XT_OFF = 256 + 589824;
  const size_t NEED = XT_OFF + (size_t)TOTPIX * CIN * 2;  // ~26.3 MB

  if (ws_size < NEED) {
    conv_naive<<<TOTPIX * COUT / 256, 256, 0, stream>>>(x, W, b, out);
    return;
  }
  char* ws = (char*)d_ws;
  u16* zp = (u16*)(ws + ZP_OFF);
  u16* Wt = (u16*)(ws + WT_OFF);
  u16* xt = (u16*)(ws + XT_OFF);

  prep_w<<<1152, 256, 0, stream>>>(W, Wt, zp);
  prep_x<<<1568, 256, 0, stream>>>(x, xt);
  conv_mfma<<<392, 512, 0, stream>>>(Wt, xt, b, out, zp);
}

// Round 8
// 91.908 us; speedup vs baseline: 4.6707x; 4.6707x over previous
//
#include <hip/hip_runtime.h>

// MyConv2D: N=32, Cin=128, H=W=56, Cout=256, K=3, stride=1, pad=1, fp32.
// R8: co-residency with a register budget that FITS (R7 post-mortem: 2
// blocks/CU needs <=128 VGPR/thread; 256x256 tile's acc alone was 128).
// 128(oc) x 256(pix) tile, BK=64, 8 waves (2M x 4N, per-wave 64x64, acc=64
// regs), single-buffered 48KB LDS -> 2 blocks/CU by VGPR AND LDS.
// Simple 2-barrier K-loop (R4-R6: schedule edits null) — the co-resident
// block hides the stage+vmcnt+barrier drain (m114 implicit overlap).
// Grid 784 = 8 XCDs x 98; adjacent same-XCD blocks share a ptile's B panel.

typedef unsigned short u16;
typedef _Float16 f16x8 __attribute__((ext_vector_type(8)));
typedef float f32x4 __attribute__((ext_vector_type(4)));

#define CIN    128
#define COUT   256
#define HW     56
#define NPIX   3136        // 56*56
#define TOTPIX 100352      // 32*3136
#define NKT    18          // K-tiles of 64 ic: 9 taps * 2 ic-halves

#define WAITVM0 asm volatile("s_waitcnt vmcnt(0)" ::: "memory")
#define BARRIER asm volatile("s_barrier" ::: "memory")

__device__ __forceinline__ void gload16(const void* g, void* l) {
  __builtin_amdgcn_global_load_lds(
      (const __attribute__((address_space(1))) void*)g,
      (__attribute__((address_space(3))) void*)l, 16, 0, 0);
}

__device__ __forceinline__ u16 f2h(float f) {
  _Float16 h = (_Float16)f;
  return __builtin_bit_cast(u16, h);
}

// ---- prep_w: W[oc][ic][3][3] fp32 -> Wt fp16 (byte-identical to R5/R6).
// e: j=e&7, ocl=(e>>3)&127, k8=(e>>10)&7, o=(e>>13)&1, t=e>>14.
// Layout = [t 18][octile 2][k8 8][ocl 128][8ic] — matches stageA exactly.
__global__ void prep_w(const float* __restrict__ W, u16* __restrict__ Wt,
                       u16* __restrict__ zp) {
  int e = blockIdx.x * 256 + threadIdx.x;     // 1152 * 256 = 294912
  if (blockIdx.x == 0 && threadIdx.x < 128) zp[threadIdx.x] = 0;
  int j   = e & 7;
  int ocl = (e >> 3) & 127;
  int k8  = (e >> 10) & 7;
  int o   = (e >> 13) & 1;
  int t   = e >> 14;                          // 0..17
  int oc = o * 128 + ocl;
  int ic = (t & 1) * 64 + k8 * 8 + j;
  Wt[e] = f2h(W[(oc * CIN + ic) * 9 + (t >> 1)]);
}

// ---- prep_x: x NCHW fp32 -> xt [n][g=ic/8][pix][8ic] fp16 (unchanged).
__global__ void prep_x(const float* __restrict__ x, u16* __restrict__ xt) {
  __shared__ unsigned int tile[64 * 65];      // [pix][icpair], +1 pad
  int b = blockIdx.x;                         // 1568 = 32 * 49
  int n = b / 49;
  int hw0 = (b % 49) * 64;
  int tid = threadIdx.x;
  const float* xb = x + (size_t)n * CIN * NPIX + hw0;
  #pragma unroll
  for (int i = 0; i < 16; ++i) {
    int e = tid + i * 256;
    int icp = e >> 6;
    int pix = e & 63;
    float a = xb[(size_t)(2 * icp) * NPIX + pix];
    float c = xb[(size_t)(2 * icp + 1) * NPIX + pix];
    tile[pix * 65 + icp] = (unsigned)f2h(a) | ((unsigned)f2h(c) << 16);
  }
  __syncthreads();
  #pragma unroll
  for (int i = 0; i < 4; ++i) {
    int e = tid + i * 256;
    int g = e >> 6;
    int pix = e & 63;
    uint4 v;
    v.x = tile[pix * 65 + g * 4 + 0];
    v.y = tile[pix * 65 + g * 4 + 1];
    v.z = tile[pix * 65 + g * 4 + 2];
    v.w = tile[pix * 65 + g * 4 + 3];
    *(uint4*)(xt + ((size_t)(n * 16 + g) * NPIX + hw0 + pix) * 8) = v;
  }
}

__global__ __launch_bounds__(512, 4) void conv_mfma(
    const u16* __restrict__ Wt, const u16* __restrict__ xt,
    const float* __restrict__ bias, float* __restrict__ out,
    const u16* __restrict__ zp) {
  // LDS 48KB: A [k8 8][ocl 128][8] = 16KB at 0 | B [k8 8][pixl 256][8] = 32KB at 8192.
  __shared__ __align__(16) u16 lds[24576];

  int tid  = threadIdx.x;                     // 0..511
  int lane = tid & 63;
  int wv   = tid >> 6;                        // 0..7
  int bid  = blockIdx.x;                      // 0..783
  int wgid = (bid & 7) * 98 + (bid >> 3);     // XCD swizzle (784 = 8*98)
  int octile = wgid & 1;                      // pair on same XCD shares ptile
  int ptile  = wgid >> 1;                     // 0..391

  int wm = wv >> 2, wn = wv & 3;              // 2M x 4N waves, per-wave 64x64
  int l15 = lane & 15, lg = lane >> 4;

  // B staging: thread owns pixel spix, k8 = sk8 + 2*i (i=0..3).
  int spix = tid & 255;
  int sk8  = tid >> 8;                        // 0..1
  int p = ptile * 256 + spix;
  int n = p / NPIX, r = p % NPIX, y = r / HW, xx = r % HW;
  const char* xtb = (const char*)xt;
  const char* wsrc = (const char*)Wt + (size_t)octile * 16384 + tid * 16;
  const char* zpc = (const char*)zp;

  auto stageA = [&](int t) {                  // 1024 granules, 2/thread
    const char* src = wsrc + (size_t)t * 32768;
    gload16(src, &lds[tid * 8]);
    gload16(src + 8192, &lds[tid * 8 + 4096]);
  };
  auto stageB = [&](int t) {                  // 2048 granules, 4/thread
    int tap = t >> 1, ich = t & 1;
    int t3 = tap / 3;
    int dh = t3 - 1, dw = (tap - t3 * 3) - 1;
    int iy = y + dh, ix = xx + dw;
    bool ok = (unsigned)iy < HW && (unsigned)ix < HW;
    const char* s0 = ok
        ? xtb + ((size_t)(n * 16 + ich * 8 + sk8) * NPIX + (r + dh * HW + dw)) * 16
        : zpc;
    size_t step = ok ? (size_t)2 * NPIX * 16 : 0;
    #pragma unroll
    for (int i = 0; i < 4; ++i)
      gload16(s0 + i * step, &lds[8192 + ((sk8 + 2 * i) * 256 + spix) * 8]);
  };

  f32x4 acc[4][4] = {};

  auto compute = [&]() {
    #pragma unroll
    for (int kk = 0; kk < 2; ++kk) {          // kk-split limits frag liveness
      const u16* ab = &lds[((kk * 4 + lg) * 128 + wm * 64 + l15) * 8];
      const u16* bb = &lds[8192 + ((kk * 4 + lg) * 256 + wn * 64 + l15) * 8];
      f16x8 af[4], bf[4];
      #pragma unroll
      for (int q = 0; q < 4; ++q) af[q] = *(const f16x8*)&ab[q * 128];
      #pragma unroll
      for (int q = 0; q < 4; ++q) bf[q] = *(const f16x8*)&bb[q * 128];
      __builtin_amdgcn_s_setprio(1);
      #pragma unroll
      for (int mq = 0; mq < 4; ++mq)
        #pragma unroll
        for (int nf = 0; nf < 4; ++nf)
          acc[mq][nf] = __builtin_amdgcn_mfma_f32_16x16x32_f16(
              af[mq], bf[nf], acc[mq][nf], 0, 0, 0);
      __builtin_amdgcn_s_setprio(0);
    }
  };

  stageA(0); stageB(0);
  WAITVM0; BARRIER;
  for (int t = 0; t < NKT; ++t) {
    compute();
    if (t + 1 < NKT) {
      BARRIER;                                // all waves done reading tile t
      stageA(t + 1); stageB(t + 1);
      WAITVM0; BARRIER;                       // tile t+1 in LDS
    }
  }

  // Epilogue. C/D: row(oc) = lg*4 + reg, col(pix) = l15.
  float* ob[4];
  #pragma unroll
  for (int nf = 0; nf < 4; ++nf) {
    int pp = ptile * 256 + wn * 64 + nf * 16 + l15;
    int nn = pp / NPIX, hw = pp % NPIX;
    ob[nf] = out + (size_t)nn * COUT * NPIX + hw;
  }
  #pragma unroll
  for (int mq = 0; mq < 4; ++mq) {
    int oc = octile * 128 + wm * 64 + mq * 16 + lg * 4;
    f32x4 bv = *(const f32x4*)&bias[oc];
    #pragma unroll
    for (int rr = 0; rr < 4; ++rr) {
      size_t row = (size_t)(oc + rr) * NPIX;
      #pragma unroll
      for (int nf = 0; nf < 4; ++nf)
        ob[nf][row] = acc[mq][nf][rr] + bv[rr];
    }
  }
}

// ---- fallback (only if ws too small): naive fp32 direct conv
__global__ void conv_naive(const float* __restrict__ x, const float* __restrict__ W,
                           const float* __restrict__ b, float* __restrict__ out) {
  int idx = blockIdx.x * 256 + threadIdx.x;
  int hw = idx % NPIX;
  int tmp = idx / NPIX;
  int oc = tmp % COUT;
  int n = tmp / COUT;
  int h = hw / HW, w = hw % HW;
  float acc = b[oc];
  for (int ic = 0; ic < CIN; ++ic) {
    const float* xr = x + (size_t)(n * CIN + ic) * NPIX;
    const float* wr = W + (size_t)(oc * CIN + ic) * 9;
    #pragma unroll
    for (int kh = 0; kh < 3; ++kh) {
      int ih = h + kh - 1;
      if ((unsigned)ih >= HW) continue;
      #pragma unroll
      for (int kw = 0; kw < 3; ++kw) {
        int iw = w + kw - 1;
        if ((unsigned)iw >= HW) continue;
        acc += xr[ih * HW + iw] * wr[kh * 3 + kw];
      }
    }
  }
  out[idx] = acc;
}

extern "C" void kernel_launch(void* const* d_in, const int* in_sizes, int n_in,
                              void* d_out, int out_size, void* d_ws, size_t ws_size,
                              hipStream_t stream) {
  const float* x = (const float*)d_in[0];
  const float* W = (const float*)d_in[1];
  const float* b = (const float*)d_in[2];
  float* out = (float*)d_out;

  const size_t ZP_OFF = 0;                    // 256 B zero page
  const size_t WT_OFF = 256;                  // 294912 * 2 = 589824 B
  const size_t XT_OFF = 256 + 589824;
  const size_t NEED = XT_OFF + (size_t)TOTPIX * CIN * 2;  // ~26.3 MB

  if (ws_size < NEED) {
    conv_naive<<<TOTPIX * COUT / 256, 256, 0, stream>>>(x, W, b, out);
    return;
  }
  char* ws = (char*)d_ws;
  u16* zp = (u16*)(ws + ZP_OFF);
  u16* Wt = (u16*)(ws + WT_OFF);
  u16* xt = (u16*)(ws + XT_OFF);

  prep_w<<<1152, 256, 0, stream>>>(W, Wt, zp);
  prep_x<<<1568, 256, 0, stream>>>(x, xt);
  conv_mfma<<<784, 512, 0, stream>>>(Wt, xt, b, out, zp);
}